// Round 1
// 598.727 us; speedup vs baseline: 1.0622x; 1.0622x over previous
//
#include <hip/hip_runtime.h>
#include <stdint.h>

// ---------------------------------------------------------------------------
// GAU forward on MI355X (gfx950), bf16 MFMA everywhere.
//   hid|qk = silu(x@[Wh|Wqk]+b) -> vT [2048][8192], gate [8192][2048],
//                                  q,k bf16 [8192][224] (cols 200..223 zero)
//   attn = relu(q@kT / 32)^2    bf16 (full [8192][8192] if ws allows, else 2 stripes)
//   out2 = (attn@v) * gate      bf16 [8192][2048]
//   y    = (out2@Wo + bo) * x   fp32 [8192][1024]
//
// R8: rewrite k_pv with the T2+T3+T4+T5 stack (counted-vmcnt pipelined
// schedule, HK/m201-class) instead of the m97 2-barrier loop:
//   - 256x256 tile, BK=32, FOUR LDS K-tile buffers (128 KiB), 8 waves
//     (2Mx4N), 512 thr, 1 block/CU. Stage tile t+3 during tile t into a
//     buffer free since tile t-1's closing barrier -> race-free by
//     construction (no half-tile ordering subtleties).
//   - s_waitcnt vmcnt(8) once per K-tile (2 tiles of loads stay in flight
//     across barriers; never drain to 0 in the loop). Tail wraps stage
//     addresses mod NT so the count stays exact.
//   - LDS XOR swizzle (16B slot ^= (row>>1)&3): row stride is 64 B so the
//     linear layout is an 8-way bank conflict on ds_read_b128 (the 3.4e7
//     SQ_LDS_BANK_CONFLICT). Both-sides swizzle: linear global_load_lds
//     dest + inverse-swizzled per-lane GLOBAL source + swizzled read
//     offset (folds to a per-lane constant).
//   - setprio(1) around each 16-MFMA cluster; raw s_barrier with
//     sched_barrier(0) fences (1 barrier per phase, 2 phases per K-tile).
// Block->tile mapping unchanged (A-panel shared within an XCD).
// k_hidqk / k_attn / k_final unchanged from R7.
// ---------------------------------------------------------------------------

typedef __bf16 bf16x8 __attribute__((ext_vector_type(8)));
typedef float f32x4 __attribute__((ext_vector_type(4)));

__device__ __forceinline__ uint16_t f2bf(float f) {
  uint32_t u = __builtin_bit_cast(uint32_t, f);
  u += 0x7fffu + ((u >> 16) & 1u);   // RNE; inputs are finite
  return (uint16_t)(u >> 16);
}
__device__ __forceinline__ float silu_f(float s) {
  return s / (1.f + __expf(-s));
}

__device__ __forceinline__ void gload16(const void* g, void* l) {
  __builtin_amdgcn_global_load_lds(
      (__attribute__((address_space(1))) void*)const_cast<void*>(g),
      (__attribute__((address_space(3))) void*)l, 16, 0, 0);
}

// ---------------- elementwise prep ----------------

__global__ void cast_to_bf16(const float* __restrict__ in, uint16_t* __restrict__ out, int n4) {
  int i = blockIdx.x * blockDim.x + threadIdx.x;
  if (i < n4) {
    float4 f = ((const float4*)in)[i];
    ushort4 o;
    o.x = f2bf(f.x); o.y = f2bf(f.y); o.z = f2bf(f.z); o.w = f2bf(f.w);
    ((ushort4*)out)[i] = o;
  }
}

// out[c][r] = (c < C) ? (bf16)in[r][c] : 0   ; out is [Cp][R]
__global__ void transpose_cast_pad(const float* __restrict__ in, uint16_t* __restrict__ out,
                                   int R, int C, int Cp) {
  __shared__ float tile[32][33];
  int cb = blockIdx.x * 32;
  int rb = blockIdx.y * 32;
  int tx = threadIdx.x;
  int ty = threadIdx.y;
#pragma unroll
  for (int i = 0; i < 4; ++i) {
    int r = rb + ty + i * 8;
    int c = cb + tx;
    tile[ty + i * 8][tx] = (c < C) ? in[(size_t)r * C + c] : 0.f;
  }
  __syncthreads();
#pragma unroll
  for (int i = 0; i < 4; ++i) {
    int c = cb + ty + i * 8;
    if (c < Cp) out[(size_t)c * R + rb + tx] = f2bf(tile[tx][ty + i * 8]);
  }
}

// ---------------- params ----------------

struct EpiParams {
  const float* bias;
  const float* bias2;
  const float* g0;
  const float* b0;
  const float* g1;
  const float* b1;
  const uint16_t* gate;
  const float* x;
  uint16_t* o16a;
  uint16_t* o16b;
  uint16_t* oq;
  uint16_t* ok;
  float* o32;
};

// ---------------------------------------------------------------------------
// k_hidqk: C = xb[8192,1024] @ [WhT;WqkT][4352,1024]^T, 128x128 tile.
// ---------------------------------------------------------------------------
__global__ __launch_bounds__(256) void k_hidqk(
    const uint16_t* __restrict__ A, const uint16_t* __restrict__ Bt, EpiParams p) {
  __shared__ __align__(16) uint16_t SH[128 * 64];   // As | Bs, 16 KB
  uint16_t* As = SH;
  uint16_t* Bs = SH + 4096;

  const int tid = threadIdx.x;
  const int lane = tid & 63;
  const int wave = tid >> 6;
  const int wr = (wave >> 1) * 64;
  const int wc = (wave & 1) * 64;
  const int m0 = blockIdx.y * 128;
  const int n0 = blockIdx.x * 128;
  const int lda = 1024, ldb = 1024, K = 1024;

  f32x4 acc[4][4] = {};

  const int r0 = tid >> 2;
  const int q8 = (tid & 3) * 8;
  const uint16_t* gA0 = A + (size_t)(m0 + r0) * lda + q8;
  const uint16_t* gA1 = A + (size_t)(m0 + 64 + r0) * lda + q8;
  const uint16_t* gB0 = Bt + (size_t)(n0 + r0) * ldb + q8;
  const uint16_t* gB1 = Bt + (size_t)(n0 + 64 + r0) * ldb + q8;
  uint16_t* lA0 = As + wave * 512;
  uint16_t* lA1 = As + 2048 + wave * 512;
  uint16_t* lB0 = Bs + wave * 512;
  uint16_t* lB1 = Bs + 2048 + wave * 512;

  const int fr = lane & 15;
  const int rg = lane >> 4;
  const int kq = rg * 8;

  for (int k0 = 0; k0 < K; k0 += 32) {
    __syncthreads();
    gload16(gA0 + k0, lA0);
    gload16(gA1 + k0, lA1);
    gload16(gB0 + k0, lB0);
    gload16(gB1 + k0, lB1);
    __syncthreads();

    bf16x8 a[4], b[4];
#pragma unroll
    for (int i = 0; i < 4; ++i)
      a[i] = *(const bf16x8*)(As + (wr + i * 16 + fr) * 32 + kq);
#pragma unroll
    for (int j = 0; j < 4; ++j)
      b[j] = *(const bf16x8*)(Bs + (wc + j * 16 + fr) * 32 + kq);
#pragma unroll
    for (int i = 0; i < 4; ++i)
#pragma unroll
      for (int j = 0; j < 4; ++j)
        acc[i][j] = __builtin_amdgcn_mfma_f32_16x16x32_bf16(a[i], b[j], acc[i][j], 0, 0, 0);
  }

  // C/D layout: col = lane&15, row = rg*4 + reg   [m89-verified]
  if (n0 < 2048) {
    // vT (transposed store). Arena [16 n-rows][64 m + pad] stride 72.
    __syncthreads();
    uint16_t* ar = SH + wave * 2048;
    const int lrow = lane >> 3;
    const int mc = (lane & 7) * 8;
#pragma unroll
    for (int j = 0; j < 4; ++j) {
      const float bc = p.bias[n0 + wc + j * 16 + fr];
#pragma unroll
      for (int i = 0; i < 4; ++i)
#pragma unroll
        for (int r = 0; r < 4; ++r)
          ar[fr * 72 + i * 16 + rg * 4 + r] = f2bf(silu_f(acc[i][j][r] + bc));
#pragma unroll
      for (int rr = 0; rr < 2; ++rr) {
        bf16x8 v = *(const bf16x8*)(ar + (rr * 8 + lrow) * 72 + mc);
        *(bf16x8*)(p.o16a + (size_t)(n0 + wc + j * 16 + rr * 8 + lrow) * 8192 + m0 + wr + mc) = v;
      }
    }
  } else if (n0 < 4096) {
    // gate. Arena [16 m-rows][64 n + pad] stride 72.
    __syncthreads();
    uint16_t* ar = SH + wave * 2048;
    const int lrow = lane >> 3;
    const int nc = (lane & 7) * 8;
    float bc[4];
#pragma unroll
    for (int j = 0; j < 4; ++j) bc[j] = p.bias[n0 + wc + j * 16 + fr];
#pragma unroll
    for (int i = 0; i < 4; ++i) {
#pragma unroll
      for (int j = 0; j < 4; ++j)
#pragma unroll
        for (int r = 0; r < 4; ++r)
          ar[(rg * 4 + r) * 72 + j * 16 + fr] = f2bf(silu_f(acc[i][j][r] + bc[j]));
#pragma unroll
      for (int rr = 0; rr < 2; ++rr) {
        bf16x8 v = *(const bf16x8*)(ar + (rr * 8 + lrow) * 72 + nc);
        *(bf16x8*)(p.o16b + (size_t)(m0 + wr + i * 16 + rr * 8 + lrow) * 2048 + (n0 - 2048) + wc + nc) = v;
      }
    }
  } else {
    // q,k: stride 224, cols 200..223 forced zero.
#pragma unroll
    for (int i = 0; i < 4; ++i) {
#pragma unroll
      for (int j = 0; j < 4; ++j) {
        const int row = m0 + wr + i * 16 + rg * 4;
        const int qc = n0 + wc + j * 16 + fr - 4096;   // 0..255
        if (qc < 224) {
#pragma unroll
          for (int r = 0; r < 4; ++r) {
            float qv = 0.f, kv = 0.f;
            if (qc < 200) {
              float s = silu_f(acc[i][j][r] + p.bias2[qc]);
              qv = s * p.g0[qc] + p.b0[qc];
              kv = s * p.g1[qc] + p.b1[qc];
            }
            p.oq[(size_t)(row + r) * 224 + qc] = f2bf(qv);
            p.ok[(size_t)(row + r) * 224 + qc] = f2bf(kv);
          }
        }
      }
    }
  }
}

// ---------------------------------------------------------------------------
// k_attn: attn = relu(q@kT/32)^2, K=224, 128x128 tile (R5 structure).
// ---------------------------------------------------------------------------
__global__ __launch_bounds__(256) void k_attn(
    const uint16_t* __restrict__ Q,
    const uint16_t* __restrict__ Kt,
    uint16_t* __restrict__ attn) {
  __shared__ __align__(16) uint16_t As[128 * 32];
  __shared__ __align__(16) uint16_t Bs[128 * 32];
  __shared__ __align__(16) uint16_t Ep[4][2][16 * 72];   // 18.4 KB, per-wave dbuf

  const int tid = threadIdx.x;
  const int lane = tid & 63;
  const int wave = tid >> 6;
  const int wr = (wave >> 1) * 64;
  const int wc = (wave & 1) * 64;
  const int m0 = blockIdx.y * 128;
  const int n0 = blockIdx.x * 128;
  const int lda = 224, ldb = 224, K = 224;

  f32x4 acc[4][4] = {};

  const int r0 = tid >> 2;
  const int q8 = (tid & 3) * 8;
  const uint16_t* gA0 = Q + (size_t)(m0 + r0) * lda + q8;
  const uint16_t* gA1 = Q + (size_t)(m0 + 64 + r0) * lda + q8;
  const uint16_t* gB0 = Kt + (size_t)(n0 + r0) * ldb + q8;
  const uint16_t* gB1 = Kt + (size_t)(n0 + 64 + r0) * ldb + q8;
  uint16_t* lA0 = As + wave * 512;
  uint16_t* lA1 = As + 2048 + wave * 512;
  uint16_t* lB0 = Bs + wave * 512;
  uint16_t* lB1 = Bs + 2048 + wave * 512;

  const int fr = lane & 15;
  const int rg = lane >> 4;
  const int kq = rg * 8;

  for (int k0 = 0; k0 < K; k0 += 32) {
    __syncthreads();
    gload16(gA0 + k0, lA0);
    gload16(gA1 + k0, lA1);
    gload16(gB0 + k0, lB0);
    gload16(gB1 + k0, lB1);
    __syncthreads();

    bf16x8 a[4], b[4];
#pragma unroll
    for (int i = 0; i < 4; ++i)
      a[i] = *(const bf16x8*)(As + (wr + i * 16 + fr) * 32 + kq);
#pragma unroll
    for (int j = 0; j < 4; ++j)
      b[j] = *(const bf16x8*)(Bs + (wc + j * 16 + fr) * 32 + kq);
#pragma unroll
    for (int i = 0; i < 4; ++i)
#pragma unroll
      for (int j = 0; j < 4; ++j)
        acc[i][j] = __builtin_amdgcn_mfma_f32_16x16x32_bf16(a[i], b[j], acc[i][j], 0, 0, 0);
  }

  // bounce epilogue: per i, wave-local [16 rows][64 cols] stride 72
#pragma unroll
  for (int i = 0; i < 4; ++i) {
    uint16_t* sl = Ep[wave][i & 1];
#pragma unroll
    for (int j = 0; j < 4; ++j)
#pragma unroll
      for (int r = 0; r < 4; ++r) {
        float s = fmaxf(acc[i][j][r] * 0.03125f, 0.f);
        sl[(rg * 4 + r) * 72 + j * 16 + fr] = f2bf(s * s);
      }
    const int row = lane >> 2;
    const int c0 = (lane & 3) * 16;
    bf16x8 v0 = *(const bf16x8*)(sl + row * 72 + c0);
    bf16x8 v1 = *(const bf16x8*)(sl + row * 72 + c0 + 8);
    uint16_t* dst = attn + (size_t)(m0 + wr + i * 16 + row) * 8192 + (n0 + wc + c0);
    *(bf16x8*)(dst) = v0;
    *(bf16x8*)(dst + 8) = v1;
  }
}

// ---------------------------------------------------------------------------
// k_pv: out2 = (attn@v)*gate.  256(M) x 256(N) tile, BK=32, 512 thr, 8 waves
// (2Mx4N, 128x64 per wave). 4-deep LDS K-tile ring (128 KiB), stage tile t+3
// during tile t, counted s_waitcnt vmcnt(8) once per K-tile (never 0 in the
// loop). XOR-swizzled LDS (slot ^= (row>>1)&3) via pre-swizzled global source
// (rule #21). setprio around each 16-MFMA cluster. 1 block/CU.
// ---------------------------------------------------------------------------
__global__ __launch_bounds__(512, 2) void k_pv(
    const uint16_t* __restrict__ A, int lda,
    const uint16_t* __restrict__ Bt, int ldb,
    int K, int nx, EpiParams p) {
  __shared__ __align__(16) uint16_t SH[65536];   // 4 x (A 16KB | B 16KB) = 128 KB

  const int id = blockIdx.x;
  const int bx = (id >> 3) % nx;                 // 8 blocks sharing an A-panel
  const int by = (id & 7) + 8 * (id / (8 * nx)); // sit on the same XCD
  const int m0 = by * 256;
  const int n0 = bx * 256;

  const int tid = threadIdx.x;
  const int lane = tid & 63;
  const int wave = tid >> 6;
  const int wrM = (wave >> 2) * 128;   // wave M origin (0/128)
  const int wcN = (wave & 3) * 64;     // wave N origin (0/64/128/192)

  const int fr = lane & 15;
  const int rg = lane >> 4;
  // swizzled 16B k-slot for ds_read: phys_slot = rg ^ ((row>>1)&3); row&3
  // contribution folds to a per-lane constant since wrM,i*16 are ≡0 mod 4.
  const int swz = (rg ^ ((fr >> 1) & 3)) * 8;    // element offset

  const int rdA = (wrM + fr) * 32 + swz;          // + buf*16384 + i*512
  const int rdB = 8192 + (wcN + fr) * 32 + swz;   // + buf*16384 + j*512

  // stage: linear LDS dest (gload writes base + lane*16B). lane l covers
  // row = c*128 + wave*16 + (l>>2), phys slot l&3 -> fetch logical k-slot
  // s = (l&3) ^ ((row>>1)&3) = (l&3) ^ ((l>>3)&3) from global.
  const int srow = lane >> 2;
  const int sk = ((lane & 3) ^ ((lane >> 3) & 3)) * 8;
  const uint16_t* gA0 = A + (size_t)(m0 + wave * 16 + srow) * lda + sk;
  const uint16_t* gA1 = gA0 + (size_t)128 * lda;
  const uint16_t* gB0 = Bt + (size_t)(n0 + wave * 16 + srow) * ldb + sk;
  const uint16_t* gB1 = gB0 + (size_t)128 * ldb;

  f32x4 acc[8][4] = {};
  const int NT = K >> 5;   // 256 K-tiles of 32

  // prologue: stage tiles 0,1,2 into ring slots 0,1,2 (A,A,B,B per tile)
  for (int s = 0; s < 3; ++s) {
    const int ko = s * 32;
    uint16_t* d = SH + s * 16384 + wave * 512;
    gload16(gA0 + ko, d);
    gload16(gA1 + ko, d + 4096);
    gload16(gB0 + ko, d + 8192);
    gload16(gB1 + ko, d + 12288);
  }
  asm volatile("s_waitcnt vmcnt(8)" ::: "memory");   // tile 0 landed
  __builtin_amdgcn_sched_barrier(0);
  __builtin_amdgcn_s_barrier();
  __builtin_amdgcn_sched_barrier(0);

  // One K-tile: 2 phases. Phase = [ds_read frags; issue stage; MFMA x16;
  // (vmcnt(8) at tile end); s_barrier]. Reads complete (lgkm) before MFMA,
  // MFMA before the barrier, so any stage issued after the barrier cannot
  // race a read. Stage target (t+3)&3 was last read at tile t-1. Tail
  // wraps kp_ mod NT: 4 loads/tile always issued, garbage lands in a free
  // slot and is never read -> vmcnt(8) stays exact.
#define PV_TILE(T_, B_, BS_)                                                   \
  do {                                                                         \
    const uint16_t* bA_ = SH + (B_) * 16384;                                   \
    const int kp_ = (((T_) + 3) & (NT - 1)) * 32;                              \
    uint16_t* sd_ = SH + (BS_) * 16384 + wave * 512;                           \
    bf16x8 aq[4], bq[4];                                                       \
    _Pragma("unroll") for (int j = 0; j < 4; ++j)                              \
        bq[j] = *(const bf16x8*)(bA_ + rdB + j * 512);                         \
    _Pragma("unroll") for (int i = 0; i < 4; ++i)                              \
        aq[i] = *(const bf16x8*)(bA_ + rdA + i * 512);                         \
    gload16(gA0 + kp_, sd_);                                                   \
    gload16(gA1 + kp_, sd_ + 4096);                                            \
    __builtin_amdgcn_s_setprio(1);                                             \
    _Pragma("unroll") for (int i = 0; i < 4; ++i)                              \
      _Pragma("unroll") for (int j = 0; j < 4; ++j)                            \
          acc[i][j] = __builtin_amdgcn_mfma_f32_16x16x32_bf16(                 \
              aq[i], bq[j], acc[i][j], 0, 0, 0);                               \
    __builtin_amdgcn_s_setprio(0);                                             \
    __builtin_amdgcn_sched_barrier(0);                                         \
    __builtin_amdgcn_s_barrier();                                              \
    __builtin_amdgcn_sched_barrier(0);                                         \
    _Pragma("unroll") for (int i = 0; i < 4; ++i)                              \
        aq[i] = *(const bf16x8*)(bA_ + rdA + (4 + i) * 512);                   \
    gload16(gB0 + kp_, sd_ + 8192);                                            \
    gload16(gB1 + kp_, sd_ + 12288);                                           \
    __builtin_amdgcn_s_setprio(1);                                             \
    _Pragma("unroll") for (int i = 0; i < 4; ++i)                              \
      _Pragma("unroll") for (int j = 0; j < 4; ++j)                            \
          acc[4 + i][j] = __builtin_amdgcn_mfma_f32_16x16x32_bf16(             \
              aq[i], bq[j], acc[4 + i][j], 0, 0, 0);                           \
    __builtin_amdgcn_s_setprio(0);                                             \
    asm volatile("s_waitcnt vmcnt(8)" ::: "memory");                           \
    __builtin_amdgcn_sched_barrier(0);                                         \
    __builtin_amdgcn_s_barrier();                                              \
    __builtin_amdgcn_sched_barrier(0);                                         \
  } while (0)

  for (int t0 = 0; t0 < NT; t0 += 4) {
    PV_TILE(t0 + 0, 0, 3);
    PV_TILE(t0 + 1, 1, 0);
    PV_TILE(t0 + 2, 2, 1);
    PV_TILE(t0 + 3, 3, 2);
  }
#undef PV_TILE

  // drain wrapped tail stages before reusing LDS as the epilogue arena
  asm volatile("s_waitcnt vmcnt(0)" ::: "memory");
  __builtin_amdgcn_sched_barrier(0);
  __builtin_amdgcn_s_barrier();
  __builtin_amdgcn_sched_barrier(0);

  // epilogue: per-wave [16][72] arena bounce, 16B gate loads + stores
  uint16_t* ar = SH + wave * 2048;
  const int lrow = lane >> 3;
  const int nc = (lane & 7) * 8;
#pragma unroll
  for (int i = 0; i < 8; ++i) {
#pragma unroll
    for (int j = 0; j < 4; ++j)
#pragma unroll
      for (int r = 0; r < 4; ++r)
        ar[(rg * 4 + r) * 72 + j * 16 + fr] = f2bf(acc[i][j][r]);
#pragma unroll
    for (int rr = 0; rr < 2; ++rr) {
      const size_t base = (size_t)(m0 + wrM + i * 16 + rr * 8 + lrow) * 2048 + n0 + wcN + nc;
      bf16x8 v = *(const bf16x8*)(ar + (rr * 8 + lrow) * 72 + nc);
      bf16x8 g = *(const bf16x8*)(p.gate + base);
      bf16x8 o;
#pragma unroll
      for (int e = 0; e < 8; ++e) o[e] = (__bf16)((float)v[e] * (float)g[e]);
      *(bf16x8*)(p.o16a + base) = o;
    }
  }
}

// ---------------------------------------------------------------------------
// k_final: y = (out2g@WoT^T + bo) * x, fp32 out. 128x128, K=2048.
// ---------------------------------------------------------------------------
__global__ __launch_bounds__(256) void k_final(
    const uint16_t* __restrict__ A,
    const uint16_t* __restrict__ Bt, EpiParams p) {
  __shared__ __align__(16) uint16_t As[128 * 32];
  __shared__ __align__(16) uint16_t Bs[128 * 32];

  const int tid = threadIdx.x;
  const int lane = tid & 63;
  const int wave = tid >> 6;
  const int wr = (wave >> 1) * 64;
  const int wc = (wave & 1) * 64;
  const int m0 = blockIdx.y * 128;
  const int n0 = blockIdx.x * 128;
  const int lda = 2048, ldb = 2048, K = 2048;

  f32x4 acc[4][4] = {};

  const int r0 = tid >> 2;
  const int q8 = (tid & 3) * 8;
  const uint16_t* gA0 = A + (size_t)(m0 + r0) * lda + q8;
  const uint16_t* gA1 = A + (size_t)(m0 + 64 + r0) * lda + q8;
  const uint16_t* gB0 = Bt + (size_t)(n0 + r0) * ldb + q8;
  const uint16_t* gB1 = Bt + (size_t)(n0 + 64 + r0) * ldb + q8;
  uint16_t* lA0 = As + wave * 512;
  uint16_t* lA1 = As + 2048 + wave * 512;
  uint16_t* lB0 = Bs + wave * 512;
  uint16_t* lB1 = Bs + 2048 + wave * 512;

  const int fr = lane & 15;
  const int kq = (lane >> 4) * 8;

  for (int k0 = 0; k0 < K; k0 += 32) {
    __syncthreads();
    gload16(gA0 + k0, lA0);
    gload16(gA1 + k0, lA1);
    gload16(gB0 + k0, lB0);
    gload16(gB1 + k0, lB1);
    __syncthreads();

    bf16x8 a[4], b[4];
#pragma unroll
    for (int i = 0; i < 4; ++i)
      a[i] = *(const bf16x8*)(As + (wr + i * 16 + fr) * 32 + kq);
#pragma unroll
    for (int j = 0; j < 4; ++j)
      b[j] = *(const bf16x8*)(Bs + (wc + j * 16 + fr) * 32 + kq);
#pragma unroll
    for (int i = 0; i < 4; ++i)
#pragma unroll
      for (int j = 0; j < 4; ++j)
        acc[i][j] = __builtin_amdgcn_mfma_f32_16x16x32_bf16(a[i], b[j], acc[i][j], 0, 0, 0);
  }

#pragma unroll
  for (int i = 0; i < 4; ++i) {
#pragma unroll
    for (int j = 0; j < 4; ++j) {
      const int row = m0 + wr + i * 16 + (lane >> 4) * 4;
      const int col = n0 + wc + j * 16 + fr;
      const float bc = p.bias[col];
#pragma unroll
      for (int r = 0; r < 4; ++r) {
        size_t idx = (size_t)(row + r) * 1024 + col;
        p.o32[idx] = (acc[i][j][r] + bc) * p.x[idx];
      }
    }
  }
}

// ---------------- launch ----------------

extern "C" void kernel_launch(void* const* d_in, const int* in_sizes, int n_in,
                              void* d_out, int out_size, void* d_ws, size_t ws_size,
                              hipStream_t stream) {
  const float* x        = (const float*)d_in[0];
  const float* W_hidden = (const float*)d_in[1];
  const float* b_hidden = (const float*)d_in[2];
  const float* W_qk     = (const float*)d_in[3];
  const float* b_qk     = (const float*)d_in[4];
  const float* gamma    = (const float*)d_in[5];
  const float* beta     = (const float*)d_in[6];
  const float* W_out    = (const float*)d_in[7];
  const float* b_out    = (const float*)d_in[8];
  float* out = (float*)d_out;

  const bool fullM = ws_size >= (236ull << 20);
  const size_t region0 = fullM ? (128ull << 20) : (64ull << 20);

  char* base = (char*)d_ws;
  uint16_t* xb    = (uint16_t*)(base);                         // 16 MB  [8192][1024]
  uint16_t* WhT   = (uint16_t*)(base + (16ull << 20));         //  8 MB  [4096][1024]
  uint16_t* WqkT  = (uint16_t*)(base + (24ull << 20));         // .5 MB  [256][1024]
  uint16_t* attnB = (uint16_t*)(base);                         // 64/128 MB
  char* tail = base + region0;
  uint16_t* WoT   = (uint16_t*)(tail);                         //  4 MB  [1024][2048]
  uint16_t* q     = (uint16_t*)(tail + (4ull << 20));          // 3.5 MB [8192][224]
  uint16_t* kk    = (uint16_t*)(tail + (8ull << 20));          // 3.5 MB
  uint16_t* vT    = (uint16_t*)(tail + (12ull << 20));         // 32 MB  [2048][8192]
  uint16_t* gate  = (uint16_t*)(tail + (44ull << 20));         // 32 MB  [8192][2048]
  uint16_t* out2g = (uint16_t*)(tail + (76ull << 20));         // 32 MB  [8192][2048]
  (void)in_sizes; (void)n_in; (void)out_size;

  // prep
  cast_to_bf16<<<(8192 * 1024 / 4) / 256, 256, 0, stream>>>(x, xb, 8192 * 1024 / 4);
  transpose_cast_pad<<<dim3(4096 / 32, 1024 / 32), dim3(32, 8), 0, stream>>>(W_hidden, WhT, 1024, 4096, 4096);
  transpose_cast_pad<<<dim3(256 / 32, 1024 / 32), dim3(32, 8), 0, stream>>>(W_qk, WqkT, 1024, 200, 256);
  transpose_cast_pad<<<dim3(1024 / 32, 2048 / 32), dim3(32, 8), 0, stream>>>(W_out, WoT, 2048, 1024, 1024);

  // fused hid + qk   (N = 4096 + 256 = 4352)
  {
    EpiParams p{};
    p.bias = b_hidden; p.bias2 = b_qk;
    p.g0 = gamma; p.b0 = beta; p.g1 = gamma + 200; p.b1 = beta + 200;
    p.o16a = vT; p.o16b = gate; p.oq = q; p.ok = kk;
    k_hidqk<<<dim3(34, 64), 256, 0, stream>>>(xb, WhT, p);
  }

  if (fullM) {
    k_attn<<<dim3(64, 64), 256, 0, stream>>>(q, kk, attnB);
    {
      EpiParams p{};
      p.gate = gate; p.o16a = out2g;
      k_pv<<<dim3(8 * 32), 512, 0, stream>>>(attnB, 8192, vT, 8192, 8192, 8, p);
    }
  } else {
    for (int s = 0; s < 2; ++s) {
      k_attn<<<dim3(64, 32), 256, 0, stream>>>(q + (size_t)s * 4096 * 224, kk, attnB);
      {
        EpiParams p{};
        p.gate = gate + (size_t)s * 4096 * 2048;
        p.o16a = out2g + (size_t)s * 4096 * 2048;
        k_pv<<<dim3(8 * 16), 512, 0, stream>>>(attnB, 8192, vT, 8192, 8192, 8, p);
      }
    }
  }

  // y = (out2g@Wo + bo) * x
  {
    EpiParams p{};
    p.bias = b_out; p.x = x; p.o32 = out;
    k_final<<<dim3(8, 64), 256, 0, stream>>>(out2g, WoT, p);
  }
}

// Round 2
// 570.488 us; speedup vs baseline: 1.1148x; 1.0495x over previous
//
#include <hip/hip_runtime.h>
#include <stdint.h>

// ---------------------------------------------------------------------------
// GAU forward on MI355X (gfx950), bf16 MFMA everywhere.
//   hid|qk = silu(x@[Wh|Wqk]+b) -> vT [2048][8192], gate [8192][2048],
//                                  q,k bf16 [8192][256] (cols 200..255 zero)
//   attn = relu(q@kT / 32)^2    bf16 (full [8192][8192] if ws allows, else 2 stripes)
//   out2 = (attn@v) * gate      bf16 [8192][2048]
//   y    = (out2@Wo + bo) * x   fp32 [8192][1024]
//
// R9: (a) k_pv: drop the mid-tile barrier (it protected nothing: both
// phases read the same ring slot and stage a different one). One
// vmcnt(8)+s_barrier per K-tile. R8 showed ~425 stall cyc per phase at
// 2 barriers/tile (871 ns/tile vs 518 ideal); halving barrier count
// should land ~74% MfmaUtil. (b) Port the ring-4 single-barrier
// counted-vmcnt swizzled template to k_hidqk / k_attn / k_final at 128²
// (64 KB ring -> 2 blocks/CU so one block's barrier stall hides under
// the other). k_attn K padded 224->256 (q/k stride 256, zeros beyond
// 200) so NT is a power of two. All kernels drain vmcnt(0) before LDS
// reuse / exit (wrapped tail stages must not hit a reassigned LDS block).
// ---------------------------------------------------------------------------

typedef __bf16 bf16x8 __attribute__((ext_vector_type(8)));
typedef float f32x4 __attribute__((ext_vector_type(4)));

__device__ __forceinline__ uint16_t f2bf(float f) {
  uint32_t u = __builtin_bit_cast(uint32_t, f);
  u += 0x7fffu + ((u >> 16) & 1u);   // RNE; inputs are finite
  return (uint16_t)(u >> 16);
}
__device__ __forceinline__ float silu_f(float s) {
  return s / (1.f + __expf(-s));
}

__device__ __forceinline__ void gload16(const void* g, void* l) {
  __builtin_amdgcn_global_load_lds(
      (__attribute__((address_space(1))) void*)const_cast<void*>(g),
      (__attribute__((address_space(3))) void*)l, 16, 0, 0);
}

// ---------------- elementwise prep ----------------

__global__ void cast_to_bf16(const float* __restrict__ in, uint16_t* __restrict__ out, int n4) {
  int i = blockIdx.x * blockDim.x + threadIdx.x;
  if (i < n4) {
    float4 f = ((const float4*)in)[i];
    ushort4 o;
    o.x = f2bf(f.x); o.y = f2bf(f.y); o.z = f2bf(f.z); o.w = f2bf(f.w);
    ((ushort4*)out)[i] = o;
  }
}

// out[c][r] = (c < C) ? (bf16)in[r][c] : 0   ; out is [Cp][R]
__global__ void transpose_cast_pad(const float* __restrict__ in, uint16_t* __restrict__ out,
                                   int R, int C, int Cp) {
  __shared__ float tile[32][33];
  int cb = blockIdx.x * 32;
  int rb = blockIdx.y * 32;
  int tx = threadIdx.x;
  int ty = threadIdx.y;
#pragma unroll
  for (int i = 0; i < 4; ++i) {
    int r = rb + ty + i * 8;
    int c = cb + tx;
    tile[ty + i * 8][tx] = (c < C) ? in[(size_t)r * C + c] : 0.f;
  }
  __syncthreads();
#pragma unroll
  for (int i = 0; i < 4; ++i) {
    int c = cb + ty + i * 8;
    if (c < Cp) out[(size_t)c * R + rb + tx] = f2bf(tile[tx][ty + i * 8]);
  }
}

// ---------------- params ----------------

struct EpiParams {
  const float* bias;
  const float* bias2;
  const float* g0;
  const float* b0;
  const float* g1;
  const float* b1;
  const uint16_t* gate;
  const float* x;
  uint16_t* o16a;
  uint16_t* o16b;
  uint16_t* oq;
  uint16_t* ok;
  float* o32;
};

// ---------------------------------------------------------------------------
// Shared 128x128 ring-4 K-loop (4 waves, BK=32, 64 KB LDS, 2 blocks/CU).
// Requires in scope: SH (uint16_t[32768]), NT (pow2), wave, rdA, rdB,
// gA0,gA1,gB0,gB1 (swizzled-source stage pointers), acc[4][4].
// Slot s: A at s*8192, B at s*8192+4096. Stage tile t+3 during tile t;
// vmcnt(8) once per tile (2 tiles of loads stay in flight).
// ---------------------------------------------------------------------------
#define TILE128(T_, B_, BS_)                                                   \
  do {                                                                         \
    const uint16_t* base_ = SH + (B_) * 8192;                                  \
    const int kp_ = (((T_) + 3) & (NT - 1)) * 32;                              \
    uint16_t* sd_ = SH + (BS_) * 8192 + wave * 512;                            \
    gload16(gA0 + kp_, sd_);                                                   \
    gload16(gA1 + kp_, sd_ + 2048);                                            \
    gload16(gB0 + kp_, sd_ + 4096);                                            \
    gload16(gB1 + kp_, sd_ + 6144);                                            \
    bf16x8 a_[4], b_[4];                                                       \
    _Pragma("unroll") for (int j = 0; j < 4; ++j)                              \
        b_[j] = *(const bf16x8*)(base_ + rdB + j * 512);                       \
    _Pragma("unroll") for (int i = 0; i < 4; ++i)                              \
        a_[i] = *(const bf16x8*)(base_ + rdA + i * 512);                       \
    __builtin_amdgcn_s_setprio(1);                                             \
    _Pragma("unroll") for (int i = 0; i < 4; ++i)                              \
      _Pragma("unroll") for (int j = 0; j < 4; ++j)                            \
          acc[i][j] = __builtin_amdgcn_mfma_f32_16x16x32_bf16(                 \
              a_[i], b_[j], acc[i][j], 0, 0, 0);                               \
    __builtin_amdgcn_s_setprio(0);                                             \
    asm volatile("s_waitcnt vmcnt(8)" ::: "memory");                           \
    __builtin_amdgcn_sched_barrier(0);                                         \
    __builtin_amdgcn_s_barrier();                                              \
    __builtin_amdgcn_sched_barrier(0);                                         \
  } while (0)

#define RING_LOOP128()                                                         \
  do {                                                                         \
    _Pragma("unroll") for (int s_ = 0; s_ < 3; ++s_) {                         \
      uint16_t* d_ = SH + s_ * 8192 + wave * 512;                              \
      gload16(gA0 + s_ * 32, d_);                                              \
      gload16(gA1 + s_ * 32, d_ + 2048);                                       \
      gload16(gB0 + s_ * 32, d_ + 4096);                                       \
      gload16(gB1 + s_ * 32, d_ + 6144);                                       \
    }                                                                          \
    asm volatile("s_waitcnt vmcnt(8)" ::: "memory");                           \
    __builtin_amdgcn_sched_barrier(0);                                         \
    __builtin_amdgcn_s_barrier();                                              \
    __builtin_amdgcn_sched_barrier(0);                                         \
    for (int t0_ = 0; t0_ < NT; t0_ += 4) {                                    \
      TILE128(t0_ + 0, 0, 3);                                                  \
      TILE128(t0_ + 1, 1, 0);                                                  \
      TILE128(t0_ + 2, 2, 1);                                                  \
      TILE128(t0_ + 3, 3, 2);                                                  \
    }                                                                          \
    asm volatile("s_waitcnt vmcnt(0)" ::: "memory");                           \
    __builtin_amdgcn_sched_barrier(0);                                         \
    __syncthreads();                                                           \
  } while (0)

// ---------------------------------------------------------------------------
// k_hidqk: C = xb[8192,1024] @ [WhT;WqkT][4352,1024]^T, 128x128 tile.
// ---------------------------------------------------------------------------
__global__ __launch_bounds__(256, 2) void k_hidqk(
    const uint16_t* __restrict__ A, const uint16_t* __restrict__ Bt, EpiParams p) {
  __shared__ __align__(16) uint16_t SH[32768];   // 4 ring slots x (A|B), 64 KB

  const int tid = threadIdx.x;
  const int lane = tid & 63;
  const int wave = tid >> 6;
  const int wr = (wave >> 1) * 64;
  const int wc = (wave & 1) * 64;
  const int m0 = blockIdx.y * 128;
  const int n0 = blockIdx.x * 128;
  const int lda = 1024, ldb = 1024;
  const int NT = 32;   // K=1024

  f32x4 acc[4][4] = {};

  const int fr = lane & 15;
  const int rg = lane >> 4;
  const int swz = (rg ^ ((fr >> 1) & 3)) * 8;
  const int rdA = (wr + fr) * 32 + swz;
  const int rdB = 4096 + (wc + fr) * 32 + swz;

  const int srow = lane >> 2;
  const int sk = ((lane & 3) ^ ((lane >> 3) & 3)) * 8;
  const uint16_t* gA0 = A + (size_t)(m0 + wave * 16 + srow) * lda + sk;
  const uint16_t* gA1 = gA0 + (size_t)64 * lda;
  const uint16_t* gB0 = Bt + (size_t)(n0 + wave * 16 + srow) * ldb + sk;
  const uint16_t* gB1 = gB0 + (size_t)64 * ldb;

  RING_LOOP128();

  // C/D layout: col = lane&15, row = rg*4 + reg   [m89-verified]
  if (n0 < 2048) {
    // vT (transposed store). Arena [16 n-rows][64 m + pad] stride 72.
    uint16_t* ar = SH + wave * 2048;
    const int lrow = lane >> 3;
    const int mc = (lane & 7) * 8;
#pragma unroll
    for (int j = 0; j < 4; ++j) {
      const float bc = p.bias[n0 + wc + j * 16 + fr];
#pragma unroll
      for (int i = 0; i < 4; ++i)
#pragma unroll
        for (int r = 0; r < 4; ++r)
          ar[fr * 72 + i * 16 + rg * 4 + r] = f2bf(silu_f(acc[i][j][r] + bc));
#pragma unroll
      for (int rr = 0; rr < 2; ++rr) {
        bf16x8 v = *(const bf16x8*)(ar + (rr * 8 + lrow) * 72 + mc);
        *(bf16x8*)(p.o16a + (size_t)(n0 + wc + j * 16 + rr * 8 + lrow) * 8192 + m0 + wr + mc) = v;
      }
    }
  } else if (n0 < 4096) {
    // gate. Arena [16 m-rows][64 n + pad] stride 72.
    uint16_t* ar = SH + wave * 2048;
    const int lrow = lane >> 3;
    const int nc = (lane & 7) * 8;
    float bc[4];
#pragma unroll
    for (int j = 0; j < 4; ++j) bc[j] = p.bias[n0 + wc + j * 16 + fr];
#pragma unroll
    for (int i = 0; i < 4; ++i) {
#pragma unroll
      for (int j = 0; j < 4; ++j)
#pragma unroll
        for (int r = 0; r < 4; ++r)
          ar[(rg * 4 + r) * 72 + j * 16 + fr] = f2bf(silu_f(acc[i][j][r] + bc[j]));
#pragma unroll
      for (int rr = 0; rr < 2; ++rr) {
        bf16x8 v = *(const bf16x8*)(ar + (rr * 8 + lrow) * 72 + nc);
        *(bf16x8*)(p.o16b + (size_t)(m0 + wr + i * 16 + rr * 8 + lrow) * 2048 + (n0 - 2048) + wc + nc) = v;
      }
    }
  } else {
    // q,k: stride 256, cols 200..255 forced zero.
#pragma unroll
    for (int i = 0; i < 4; ++i) {
#pragma unroll
      for (int j = 0; j < 4; ++j) {
        const int row = m0 + wr + i * 16 + rg * 4;
        const int qc = n0 + wc + j * 16 + fr - 4096;   // 0..255
#pragma unroll
        for (int r = 0; r < 4; ++r) {
          float qv = 0.f, kv = 0.f;
          if (qc < 200) {
            float s = silu_f(acc[i][j][r] + p.bias2[qc]);
            qv = s * p.g0[qc] + p.b0[qc];
            kv = s * p.g1[qc] + p.b1[qc];
          }
          p.oq[(size_t)(row + r) * 256 + qc] = f2bf(qv);
          p.ok[(size_t)(row + r) * 256 + qc] = f2bf(kv);
        }
      }
    }
  }
}

// ---------------------------------------------------------------------------
// k_attn: attn = relu(q@kT/32)^2, K=256 (padded), 128x128 tile, ring-4.
// ---------------------------------------------------------------------------
__global__ __launch_bounds__(256, 2) void k_attn(
    const uint16_t* __restrict__ Q,
    const uint16_t* __restrict__ Kt,
    uint16_t* __restrict__ attn) {
  __shared__ __align__(16) uint16_t SH[32768];

  const int tid = threadIdx.x;
  const int lane = tid & 63;
  const int wave = tid >> 6;
  const int wr = (wave >> 1) * 64;
  const int wc = (wave & 1) * 64;
  const int m0 = blockIdx.y * 128;
  const int n0 = blockIdx.x * 128;
  const int lda = 256, ldb = 256;
  const int NT = 8;   // K=256

  f32x4 acc[4][4] = {};

  const int fr = lane & 15;
  const int rg = lane >> 4;
  const int swz = (rg ^ ((fr >> 1) & 3)) * 8;
  const int rdA = (wr + fr) * 32 + swz;
  const int rdB = 4096 + (wc + fr) * 32 + swz;

  const int srow = lane >> 2;
  const int sk = ((lane & 3) ^ ((lane >> 3) & 3)) * 8;
  const uint16_t* gA0 = Q + (size_t)(m0 + wave * 16 + srow) * lda + sk;
  const uint16_t* gA1 = gA0 + (size_t)64 * lda;
  const uint16_t* gB0 = Kt + (size_t)(n0 + wave * 16 + srow) * ldb + sk;
  const uint16_t* gB1 = gB0 + (size_t)64 * ldb;

  RING_LOOP128();

  // bounce epilogue: per i, wave-local [16 rows][64 cols] stride 72, dbuf
#pragma unroll
  for (int i = 0; i < 4; ++i) {
    uint16_t* sl = SH + wave * 4096 + (i & 1) * 2048;
#pragma unroll
    for (int j = 0; j < 4; ++j)
#pragma unroll
      for (int r = 0; r < 4; ++r) {
        float s = fmaxf(acc[i][j][r] * 0.03125f, 0.f);
        sl[(rg * 4 + r) * 72 + j * 16 + fr] = f2bf(s * s);
      }
    const int row = lane >> 2;
    const int c0 = (lane & 3) * 16;
    bf16x8 v0 = *(const bf16x8*)(sl + row * 72 + c0);
    bf16x8 v1 = *(const bf16x8*)(sl + row * 72 + c0 + 8);
    uint16_t* dst = attn + (size_t)(m0 + wr + i * 16 + row) * 8192 + (n0 + wc + c0);
    *(bf16x8*)(dst) = v0;
    *(bf16x8*)(dst + 8) = v1;
  }
}

// ---------------------------------------------------------------------------
// k_pv: out2 = (attn@v)*gate.  256x256 tile, BK=32, 512 thr, 8 waves
// (2Mx4N, 128x64 per wave). Ring-4 (128 KiB), ONE vmcnt(8)+barrier per
// K-tile (R9: mid-tile barrier removed — no hazard between the two MFMA
// halves; both read the same slot and stage a different one).
// ---------------------------------------------------------------------------
__global__ __launch_bounds__(512, 2) void k_pv(
    const uint16_t* __restrict__ A, int lda,
    const uint16_t* __restrict__ Bt, int ldb,
    int K, int nx, EpiParams p) {
  __shared__ __align__(16) uint16_t SH[65536];   // 4 x (A 16KB | B 16KB) = 128 KB

  const int id = blockIdx.x;
  const int bx = (id >> 3) % nx;                 // 8 blocks sharing an A-panel
  const int by = (id & 7) + 8 * (id / (8 * nx)); // sit on the same XCD
  const int m0 = by * 256;
  const int n0 = bx * 256;

  const int tid = threadIdx.x;
  const int lane = tid & 63;
  const int wave = tid >> 6;
  const int wrM = (wave >> 2) * 128;   // wave M origin (0/128)
  const int wcN = (wave & 3) * 64;     // wave N origin (0/64/128/192)

  const int fr = lane & 15;
  const int rg = lane >> 4;
  const int swz = (rg ^ ((fr >> 1) & 3)) * 8;

  const int rdA = (wrM + fr) * 32 + swz;          // + buf*16384 + i*512
  const int rdB = 8192 + (wcN + fr) * 32 + swz;   // + buf*16384 + j*512

  const int srow = lane >> 2;
  const int sk = ((lane & 3) ^ ((lane >> 3) & 3)) * 8;
  const uint16_t* gA0 = A + (size_t)(m0 + wave * 16 + srow) * lda + sk;
  const uint16_t* gA1 = gA0 + (size_t)128 * lda;
  const uint16_t* gB0 = Bt + (size_t)(n0 + wave * 16 + srow) * ldb + sk;
  const uint16_t* gB1 = gB0 + (size_t)128 * ldb;

  f32x4 acc[8][4] = {};
  const int NT = K >> 5;   // 256 K-tiles of 32

  // prologue: stage tiles 0,1,2 into ring slots 0,1,2
  for (int s = 0; s < 3; ++s) {
    const int ko = s * 32;
    uint16_t* d = SH + s * 16384 + wave * 512;
    gload16(gA0 + ko, d);
    gload16(gA1 + ko, d + 4096);
    gload16(gB0 + ko, d + 8192);
    gload16(gB1 + ko, d + 12288);
  }
  asm volatile("s_waitcnt vmcnt(8)" ::: "memory");   // tile 0 landed
  __builtin_amdgcn_sched_barrier(0);
  __builtin_amdgcn_s_barrier();
  __builtin_amdgcn_sched_barrier(0);

#define PV_TILE(T_, B_, BS_)                                                   \
  do {                                                                         \
    const uint16_t* bA_ = SH + (B_) * 16384;                                   \
    const int kp_ = (((T_) + 3) & (NT - 1)) * 32;                              \
    uint16_t* sd_ = SH + (BS_) * 16384 + wave * 512;                           \
    gload16(gA0 + kp_, sd_);                                                   \
    gload16(gA1 + kp_, sd_ + 4096);                                            \
    gload16(gB0 + kp_, sd_ + 8192);                                            \
    gload16(gB1 + kp_, sd_ + 12288);                                           \
    bf16x8 aq[8], bq[4];                                                       \
    _Pragma("unroll") for (int j = 0; j < 4; ++j)                              \
        bq[j] = *(const bf16x8*)(bA_ + rdB + j * 512);                         \
    _Pragma("unroll") for (int i = 0; i < 8; ++i)                              \
        aq[i] = *(const bf16x8*)(bA_ + rdA + i * 512);                         \
    __builtin_amdgcn_s_setprio(1);                                             \
    _Pragma("unroll") for (int i = 0; i < 8; ++i)                              \
      _Pragma("unroll") for (int j = 0; j < 4; ++j)                            \
          acc[i][j] = __builtin_amdgcn_mfma_f32_16x16x32_bf16(                 \
              aq[i], bq[j], acc[i][j], 0, 0, 0);                               \
    __builtin_amdgcn_s_setprio(0);                                             \
    asm volatile("s_waitcnt vmcnt(8)" ::: "memory");                           \
    __builtin_amdgcn_sched_barrier(0);                                         \
    __builtin_amdgcn_s_barrier();                                              \
    __builtin_amdgcn_sched_barrier(0);                                         \
  } while (0)

  for (int t0 = 0; t0 < NT; t0 += 4) {
    PV_TILE(t0 + 0, 0, 3);
    PV_TILE(t0 + 1, 1, 0);
    PV_TILE(t0 + 2, 2, 1);
    PV_TILE(t0 + 3, 3, 2);
  }
#undef PV_TILE

  // drain wrapped tail stages before reusing LDS as the epilogue arena
  asm volatile("s_waitcnt vmcnt(0)" ::: "memory");
  __builtin_amdgcn_sched_barrier(0);
  __builtin_amdgcn_s_barrier();
  __builtin_amdgcn_sched_barrier(0);

  // epilogue: per-wave [16][72] arena bounce, 16B gate loads + stores
  uint16_t* ar = SH + wave * 2048;
  const int lrow = lane >> 3;
  const int nc = (lane & 7) * 8;
#pragma unroll
  for (int i = 0; i < 8; ++i) {
#pragma unroll
    for (int j = 0; j < 4; ++j)
#pragma unroll
      for (int r = 0; r < 4; ++r)
        ar[(rg * 4 + r) * 72 + j * 16 + fr] = f2bf(acc[i][j][r]);
#pragma unroll
    for (int rr = 0; rr < 2; ++rr) {
      const size_t base = (size_t)(m0 + wrM + i * 16 + rr * 8 + lrow) * 2048 + n0 + wcN + nc;
      bf16x8 v = *(const bf16x8*)(ar + (rr * 8 + lrow) * 72 + nc);
      bf16x8 g = *(const bf16x8*)(p.gate + base);
      bf16x8 o;
#pragma unroll
      for (int e = 0; e < 8; ++e) o[e] = (__bf16)((float)v[e] * (float)g[e]);
      *(bf16x8*)(p.o16a + base) = o;
    }
  }
}

// ---------------------------------------------------------------------------
// k_final: y = (out2g@WoT^T + bo) * x, fp32 out. 128x128, K=2048, ring-4.
// ---------------------------------------------------------------------------
__global__ __launch_bounds__(256, 2) void k_final(
    const uint16_t* __restrict__ A,
    const uint16_t* __restrict__ Bt, EpiParams p) {
  __shared__ __align__(16) uint16_t SH[32768];

  const int tid = threadIdx.x;
  const int lane = tid & 63;
  const int wave = tid >> 6;
  const int wr = (wave >> 1) * 64;
  const int wc = (wave & 1) * 64;
  const int m0 = blockIdx.y * 128;
  const int n0 = blockIdx.x * 128;
  const int lda = 2048, ldb = 2048;
  const int NT = 64;   // K=2048

  f32x4 acc[4][4] = {};

  const int fr = lane & 15;
  const int rg = lane >> 4;
  const int swz = (rg ^ ((fr >> 1) & 3)) * 8;
  const int rdA = (wr + fr) * 32 + swz;
  const int rdB = 4096 + (wc + fr) * 32 + swz;

  const int srow = lane >> 2;
  const int sk = ((lane & 3) ^ ((lane >> 3) & 3)) * 8;
  const uint16_t* gA0 = A + (size_t)(m0 + wave * 16 + srow) * lda + sk;
  const uint16_t* gA1 = gA0 + (size_t)64 * lda;
  const uint16_t* gB0 = Bt + (size_t)(n0 + wave * 16 + srow) * ldb + sk;
  const uint16_t* gB1 = gB0 + (size_t)64 * ldb;

  RING_LOOP128();

#pragma unroll
  for (int i = 0; i < 4; ++i) {
#pragma unroll
    for (int j = 0; j < 4; ++j) {
      const int row = m0 + wr + i * 16 + rg * 4;
      const int col = n0 + wc + j * 16 + fr;
      const float bc = p.bias[col];
#pragma unroll
      for (int r = 0; r < 4; ++r) {
        size_t idx = (size_t)(row + r) * 1024 + col;
        p.o32[idx] = (acc[i][j][r] + bc) * p.x[idx];
      }
    }
  }
}

// ---------------- launch ----------------

extern "C" void kernel_launch(void* const* d_in, const int* in_sizes, int n_in,
                              void* d_out, int out_size, void* d_ws, size_t ws_size,
                              hipStream_t stream) {
  const float* x        = (const float*)d_in[0];
  const float* W_hidden = (const float*)d_in[1];
  const float* b_hidden = (const float*)d_in[2];
  const float* W_qk     = (const float*)d_in[3];
  const float* b_qk     = (const float*)d_in[4];
  const float* gamma    = (const float*)d_in[5];
  const float* beta     = (const float*)d_in[6];
  const float* W_out    = (const float*)d_in[7];
  const float* b_out    = (const float*)d_in[8];
  float* out = (float*)d_out;

  const bool fullM = ws_size >= (236ull << 20);
  const size_t region0 = fullM ? (128ull << 20) : (64ull << 20);

  char* base = (char*)d_ws;
  uint16_t* xb    = (uint16_t*)(base);                         // 16 MB  [8192][1024]
  uint16_t* WhT   = (uint16_t*)(base + (16ull << 20));         //  8 MB  [4096][1024]
  uint16_t* WqkT  = (uint16_t*)(base + (24ull << 20));         // .5 MB  [256][1024]
  uint16_t* attnB = (uint16_t*)(base);                         // 64/128 MB
  char* tail = base + region0;
  uint16_t* WoT   = (uint16_t*)(tail);                         //  4 MB  [1024][2048]
  uint16_t* q     = (uint16_t*)(tail + (4ull << 20));          //  4 MB  [8192][256]
  uint16_t* kk    = (uint16_t*)(tail + (8ull << 20));          //  4 MB
  uint16_t* vT    = (uint16_t*)(tail + (12ull << 20));         // 32 MB  [2048][8192]
  uint16_t* gate  = (uint16_t*)(tail + (44ull << 20));         // 32 MB  [8192][2048]
  uint16_t* out2g = (uint16_t*)(tail + (76ull << 20));         // 32 MB  [8192][2048]
  (void)in_sizes; (void)n_in; (void)out_size;

  // prep
  cast_to_bf16<<<(8192 * 1024 / 4) / 256, 256, 0, stream>>>(x, xb, 8192 * 1024 / 4);
  transpose_cast_pad<<<dim3(4096 / 32, 1024 / 32), dim3(32, 8), 0, stream>>>(W_hidden, WhT, 1024, 4096, 4096);
  transpose_cast_pad<<<dim3(256 / 32, 1024 / 32), dim3(32, 8), 0, stream>>>(W_qk, WqkT, 1024, 200, 256);
  transpose_cast_pad<<<dim3(1024 / 32, 2048 / 32), dim3(32, 8), 0, stream>>>(W_out, WoT, 2048, 1024, 1024);

  // fused hid + qk   (N = 4096 + 256 = 4352)
  {
    EpiParams p{};
    p.bias = b_hidden; p.bias2 = b_qk;
    p.g0 = gamma; p.b0 = beta; p.g1 = gamma + 200; p.b1 = beta + 200;
    p.o16a = vT; p.o16b = gate; p.oq = q; p.ok = kk;
    k_hidqk<<<dim3(34, 64), 256, 0, stream>>>(xb, WhT, p);
  }

  if (fullM) {
    k_attn<<<dim3(64, 64), 256, 0, stream>>>(q, kk, attnB);
    {
      EpiParams p{};
      p.gate = gate; p.o16a = out2g;
      k_pv<<<dim3(8 * 32), 512, 0, stream>>>(attnB, 8192, vT, 8192, 8192, 8, p);
    }
  } else {
    for (int s = 0; s < 2; ++s) {
      k_attn<<<dim3(64, 32), 256, 0, stream>>>(q + (size_t)s * 4096 * 256, kk, attnB);
      {
        EpiParams p{};
        p.gate = gate + (size_t)s * 4096 * 2048;
        p.o16a = out2g + (size_t)s * 4096 * 2048;
        k_pv<<<dim3(8 * 16), 512, 0, stream>>>(attnB, 8192, vT, 8192, 8192, 8, p);
      }
    }
  }

  // y = (out2g@Wo + bo) * x
  {
    EpiParams p{};
    p.bias = b_out; p.x = x; p.o32 = out;
    k_final<<<dim3(8, 64), 256, 0, stream>>>(out2g, WoT, p);
  }
}